// Round 1
// 219.012 us; speedup vs baseline: 1.0507x; 1.0507x over previous
//
#include <hip/hip_runtime.h>
#include <stdint.h>
#include <stddef.h>

typedef unsigned short u16;
typedef unsigned int   u32;

typedef __attribute__((ext_vector_type(8))) short bf16x8;
typedef __attribute__((ext_vector_type(4))) float f32x4;

__device__ __forceinline__ float b2f(u16 u)    { return __uint_as_float(((u32)u) << 16); }
__device__ __forceinline__ float b2f_lo(u32 v) { return __uint_as_float(v << 16); }
__device__ __forceinline__ float b2f_hi(u32 v) { return __uint_as_float(v & 0xFFFF0000u); }
__device__ __forceinline__ u16 f2b(float f){
  u32 x = __float_as_uint(f);
  return (u16)((x + 0x7FFFu + ((x >> 16) & 1u)) >> 16);
}

// ---------------------------------------------------------------------------
// K0a: x[b][c][w] FLOAT32 -> xt[b][w][c] bf16 (fused transpose+downconvert).
// B=4, C=256, W=8192.  grid (128 w-tiles, 4 c-tiles, 4 b) x 256 thr; 64x64 tile.
// ---------------------------------------------------------------------------
__global__ __launch_bounds__(256) void k_transpose(const float* __restrict__ x, u16* __restrict__ xt){
  __shared__ u16 tile[64 * 65];
  const int wt = blockIdx.x, ct = blockIdx.y, b = blockIdx.z;
  const int W0 = wt << 6, C0 = ct << 6;
  const int t = threadIdx.x;
#pragma unroll
  for (int it = 0; it < 4; ++it){
    const int task = t + (it << 8);          // 0..1023
    const int c = task >> 4, u = task & 15;  // c<64, u<16 (float4 chunks of 64-wide row)
    const float4 d = *(const float4*)(x + ((size_t)((b << 8) + C0 + c) << 13) + W0 + (u << 2));
    const int base = c * 65 + (u << 2);
    tile[base + 0] = f2b(d.x); tile[base + 1] = f2b(d.y);
    tile[base + 2] = f2b(d.z); tile[base + 3] = f2b(d.w);
  }
  __syncthreads();
#pragma unroll
  for (int it = 0; it < 2; ++it){
    const int task = t + (it << 8);          // 0..511
    const int wr = task >> 3, cu = task & 7; // wr<64, cu<8 (8 bf16 per chunk)
    const int cb = cu << 3;
    u32 a0 = (u32)tile[(cb + 0) * 65 + wr] | ((u32)tile[(cb + 1) * 65 + wr] << 16);
    u32 a1 = (u32)tile[(cb + 2) * 65 + wr] | ((u32)tile[(cb + 3) * 65 + wr] << 16);
    u32 a2 = (u32)tile[(cb + 4) * 65 + wr] | ((u32)tile[(cb + 5) * 65 + wr] << 16);
    u32 a3 = (u32)tile[(cb + 6) * 65 + wr] | ((u32)tile[(cb + 7) * 65 + wr] << 16);
    uint4 val = make_uint4(a0, a1, a2, a3);
    *(uint4*)(xt + ((size_t)((b << 13) + W0 + wr) << 8) + C0 + cb) = val;
  }
}

// ---------------------------------------------------------------------------
// K0b: build combined weight matrix Wall[896][256] (bf16) + fp32 bias ball[896]
// from FLOAT32 inputs.  rows 0-255: w1/b1, 256-511: w2/b2, 512-767: w3/b3,
// rows 768-831: Wf/bf (fc folded conv branch), 832-895: zero pad.
// grid 896 x 256 threads.
// ---------------------------------------------------------------------------
__global__ __launch_bounds__(256) void k_build(const float* __restrict__ w1, const float* __restrict__ b1,
                                               const float* __restrict__ w2, const float* __restrict__ b2,
                                               const float* __restrict__ w3, const float* __restrict__ b3,
                                               const float* __restrict__ fcw,
                                               u16* __restrict__ Wall, float* __restrict__ ball){
  const int r = blockIdx.x, c = threadIdx.x;
  float v = 0.f, bv = 0.f;
  if (r < 256){      v = w1[(r << 8) + c];          bv = b1[r]; }
  else if (r < 512){ v = w2[((r - 256) << 8) + c];  bv = b2[r - 256]; }
  else if (r < 768){ v = w3[((r - 512) << 8) + c];  bv = b3[r - 512]; }
  else if (r < 832){
    const int d = r - 768;
    float s = 0.f, sbias = 0.f;
#pragma unroll
    for (int h = 0; h < 4; ++h){
      const int ch = (h << 6) + d;
      const float f1 = fcw[h], f2 = fcw[4 + h], f3 = fcw[8 + h];
      s     += f1 * w1[(ch << 8) + c] + f2 * w2[(ch << 8) + c] + f3 * w3[(ch << 8) + c];
      sbias += f1 * b1[ch] + f2 * b2[ch] + f3 * b3[ch];
    }
    v = s; bv = sbias;
  }
  Wall[(r << 8) + c] = f2b(v);
  if (c == 0) ball[r] = bv;
}

// ---------------------------------------------------------------------------
// K1: GEMM  qkvt[b][w][m] = Wall[m][:] . xt[b][w][:] + ball[m],  m<832 stored.
// M=896 (7 tiles of 128), N=32768 (b,w; 128-col tiles), K=256 (BK=64).
// 256 threads = 4 waves in 2x2; each wave 64x64 via 4x4 grid of 16x16x32 MFMA.
// This round:
//   - XCD-grouped 1-D grid: all 7 mt blocks of an nt run on ONE XCD (B-tile
//     fetched from HBM once per XCD; Wall L2-resident).
//   - XOR-swizzled As/Bs (chunk ^= row&7): spreads the l15-strided fragment
//     reads over all 8 bank groups (was 16 lanes on one group).
//   - register prefetch of next K-tile issued before the MFMA cluster.
//   - epilogue transposes C through LDS (reusing As/Bs, swizzled) and stores
//     256 B contiguous per w row -> full-line HBM writes (was scattered 8 B).
// grid 1792 x 256 threads.
// ---------------------------------------------------------------------------
__global__ __launch_bounds__(256) void gemm_qkv(const u16* __restrict__ Wall, const float* __restrict__ ball,
                                                const u16* __restrict__ xt, u16* __restrict__ qkvt){
  __shared__ __align__(16) u16 sm[2 * 128 * 64];   // As | Bs, reused as 128x128 C-tile
  u16* As = sm;
  u16* Bs = sm + 128 * 64;

  // XCD-grouped mapping: bid%8 = XCD (round-robin dispatch); 224 slots per XCD,
  // mt fastest within a slot group so one nt's 7 blocks share an XCD's L2.
  const int bid = blockIdx.x;
  const int w_id = ((bid & 7) * 224) + (bid >> 3);  // 0..1791, bijective
  const int mt = w_id % 7;
  const int nt = w_id / 7;                          // 0..255
  const int b = nt >> 6;
  const int w0 = (nt & 63) << 7;
  const int tid = threadIdx.x;
  const int wave = tid >> 6, lane = tid & 63;
  const int wy = wave >> 1, wx = wave & 1;
  const int m0 = mt << 7;
  const int quad = lane >> 4, l15 = lane & 15;
  f32x4 acc[4][4] = {};

  uint4 ra[4], rb[4];
  auto stage_load = [&](int kc){
#pragma unroll
    for (int k = 0; k < 4; ++k){
      const int cid = tid + (k << 8);          // 0..1023
      const int row = cid >> 3, u = cid & 7;   // row<128, unit<8 (8 bf16 each)
      ra[k] = *(const uint4*)(Wall + ((m0 + row) << 8) + kc + (u << 3));
      rb[k] = *(const uint4*)(xt + (((size_t)((b << 13) + w0 + row)) << 8) + kc + (u << 3));
    }
  };

  stage_load(0);
#pragma unroll
  for (int kt = 0; kt < 4; ++kt){
    __syncthreads();   // previous iteration's LDS reads complete before overwrite
#pragma unroll
    for (int k = 0; k < 4; ++k){
      const int cid = tid + (k << 8);
      const int row = cid >> 3, u = (cid & 7) ^ (row & 7);   // T2 XOR swizzle
      *(uint4*)(As + (row << 6) + (u << 3)) = ra[k];
      *(uint4*)(Bs + (row << 6) + (u << 3)) = rb[k];
    }
    __syncthreads();
    if (kt < 3) stage_load((kt + 1) << 6);     // prefetch next tile under compute
#pragma unroll
    for (int ks = 0; ks < 2; ++ks){
      bf16x8 av[4], bvv[4];
#pragma unroll
      for (int i = 0; i < 4; ++i){
        const int rowA = (wy << 6) + (i << 4) + l15;
        const int ca = ((ks << 2) + quad) ^ (rowA & 7);
        av[i] = *(const bf16x8*)(As + (rowA << 6) + (ca << 3));
        const int rowB = (wx << 6) + (i << 4) + l15;
        const int cb2 = ((ks << 2) + quad) ^ (rowB & 7);
        bvv[i] = *(const bf16x8*)(Bs + (rowB << 6) + (cb2 << 3));
      }
#pragma unroll
      for (int i = 0; i < 4; ++i)
#pragma unroll
        for (int j = 0; j < 4; ++j)
          acc[i][j] = __builtin_amdgcn_mfma_f32_16x16x32_bf16(av[i], bvv[j], acc[i][j], 0, 0, 0);
    }
  }

  // --- epilogue: bias + bf16 pack into LDS as [w_local][m_local] (swizzled),
  //     then 16 B/thread coalesced stores: 256 B contiguous per w row. ---
  __syncthreads();   // all waves done reading As/Bs
#pragma unroll
  for (int i = 0; i < 4; ++i){
    const int ml = (wy << 6) + (i << 4) + (quad << 2);      // 4 consecutive m
    const float4 bias = *(const float4*)(ball + m0 + ml);
#pragma unroll
    for (int j = 0; j < 4; ++j){
      const int wl = (wx << 6) + (j << 4) + l15;
      f32x4 r = acc[i][j];
      uint2 val;
      val.x = (u32)f2b(r.x + bias.x) | ((u32)f2b(r.y + bias.y) << 16);
      val.y = (u32)f2b(r.z + bias.z) | ((u32)f2b(r.w + bias.w) << 16);
      const int byte = ((wl << 8) + (ml << 1)) ^ ((wl & 7) << 4);
      *(uint2*)((char*)sm + byte) = val;
    }
  }
  __syncthreads();
#pragma unroll
  for (int it = 0; it < 8; ++it){
    const int task = tid + (it << 8);        // 0..2047
    const int wl = task >> 4, c = task & 15; // wl<128, 16B chunk c<16
    const int mcol = m0 + (c << 3);
    if (mcol < 832){
      const int byte = ((wl << 8) + (c << 4)) ^ ((wl & 7) << 4);
      const uint4 val = *(const uint4*)((const char*)sm + byte);
      *(uint4*)(qkvt + ((size_t)((b << 13) + w0 + wl)) * 832 + mcol) = val;
    }
  }
}

// ---------------------------------------------------------------------------
// K2: windowed attention (K_ATT=7, reflect pad) + folded conv branch + combine.
// One thread per (b,h,w).  grid (32 wtiles of 256, 4 heads, 4 b) x 256 threads.
// k/v staged per 32-channel half into ONE 16.7KB LDS buffer (rotation swizzle).
// q (128B) and f (32B) per-thread from contiguous qkvt row slices.
// FLOAT32 params (wp/depw/depb/rates) and FLOAT32 output stores (coalesced).
// ---------------------------------------------------------------------------
__global__ __launch_bounds__(256) void attn_out(const u16* __restrict__ qkvt, const float* __restrict__ wp,
                                                const float* __restrict__ depw, const float* __restrict__ depb,
                                                const float* __restrict__ r1p, const float* __restrict__ r2p,
                                                float* __restrict__ out){
  __shared__ __align__(16) u16 sb[262 * 32];
  __shared__ float wpL[64];
  const int wt = blockIdx.x, h = blockIdx.y, b = blockIdx.z;
  const int w0 = wt << 8;
  const int t = threadIdx.x;
  const int w = w0 + t;
  if (t < 64) wpL[t] = wp[t];

  const u16* rowp = qkvt + ((size_t)((b << 13) + w)) * 832;
  uint4 qreg[8];
#pragma unroll
  for (int j = 0; j < 8; ++j) qreg[j] = *(const uint4*)(rowp + (h << 6) + (j << 3));
  float fv[16];
  {
    uint4 f0 = *(const uint4*)(rowp + 768 + (h << 4));
    uint4 f1 = *(const uint4*)(rowp + 768 + (h << 4) + 8);
    fv[0] = b2f_lo(f0.x); fv[1] = b2f_hi(f0.x); fv[2]  = b2f_lo(f0.y); fv[3]  = b2f_hi(f0.y);
    fv[4] = b2f_lo(f0.z); fv[5] = b2f_hi(f0.z); fv[6]  = b2f_lo(f0.w); fv[7]  = b2f_hi(f0.w);
    fv[8] = b2f_lo(f1.x); fv[9] = b2f_hi(f1.x); fv[10] = b2f_lo(f1.y); fv[11] = b2f_hi(f1.y);
    fv[12]= b2f_lo(f1.z); fv[13]= b2f_hi(f1.z); fv[14] = b2f_lo(f1.w); fv[15] = b2f_hi(f1.w);
  }

  float att[7] = {0.f,0.f,0.f,0.f,0.f,0.f,0.f};
  float qd = 0.f;

  // --- phase A: att[kk] = q . k[w+kk-3]  (two 32-channel halves) ---
#pragma unroll
  for (int half = 0; half < 2; ++half){
    __syncthreads();
    for (int idx = t; idx < 262 * 4; idx += 256){
      const int row = idx >> 2, u = idx & 3;
      int wsrc = w0 - 3 + row;
      wsrc = wsrc < 0 ? -wsrc : (wsrc > 8191 ? 16382 - wsrc : wsrc);
      const uint4 d = *(const uint4*)(qkvt + ((size_t)((b << 13) + wsrc)) * 832 + 256 + (h << 6) + (half << 5) + (u << 3));
      *(uint4*)(sb + (row << 5) + (((u + (row >> 1)) & 3) << 3)) = d;
    }
    __syncthreads();
#pragma unroll
    for (int jj = 0; jj < 4; ++jj){
      const int j = (half << 2) + jj;
      float qf[8];
      {
        const uint4 q4 = qreg[j];
        qf[0] = b2f_lo(q4.x); qf[1] = b2f_hi(q4.x); qf[2] = b2f_lo(q4.y); qf[3] = b2f_hi(q4.y);
        qf[4] = b2f_lo(q4.z); qf[5] = b2f_hi(q4.z); qf[6] = b2f_lo(q4.w); qf[7] = b2f_hi(q4.w);
      }
#pragma unroll
      for (int e = 0; e < 8; ++e) qd += qf[e] * wpL[(j << 3) + e];
#pragma unroll
      for (int kk = 0; kk < 7; ++kk){
        const int r = t + kk;
        const uint4 kv = *(const uint4*)(sb + (r << 5) + (((jj + (r >> 1)) & 3) << 3));
        float a = att[kk];
        a += qf[0] * b2f_lo(kv.x) + qf[1] * b2f_hi(kv.x) + qf[2] * b2f_lo(kv.y) + qf[3] * b2f_hi(kv.y)
           + qf[4] * b2f_lo(kv.z) + qf[5] * b2f_hi(kv.z) + qf[6] * b2f_lo(kv.w) + qf[7] * b2f_hi(kv.w);
        att[kk] = a;
      }
    }
  }

  // --- positional term + scale + softmax over the 7-window ---
  const float locw = -1.f + (2.f / 8191.f) * (float)w;
  float mx = -1e30f;
#pragma unroll
  for (int kk = 0; kk < 7; ++kk){
    int wr = w + kk - 3;
    wr = wr < 0 ? -wr : (wr > 8191 ? 16382 - wr : wr);
    const float lr = -1.f + (2.f / 8191.f) * (float)wr;
    att[kk] = 0.125f * (att[kk] + (locw - lr) * qd);
    mx = fmaxf(mx, att[kk]);
  }
  float p[7]; float ssum = 0.f;
#pragma unroll
  for (int kk = 0; kk < 7; ++kk){ p[kk] = __expf(att[kk] - mx); ssum += p[kk]; }
  const float inv = 1.f / ssum;
#pragma unroll
  for (int kk = 0; kk < 7; ++kk) p[kk] *= inv;

  const float r1 = r1p[0];
  const float r2 = r2p[0];

  // --- phase B: out = rate1 * (P.V) + rate2 * (dep_w * f + dep_b) ---
#pragma unroll
  for (int half = 0; half < 2; ++half){
    __syncthreads();
    for (int idx = t; idx < 262 * 4; idx += 256){
      const int row = idx >> 2, u = idx & 3;
      int wsrc = w0 - 3 + row;
      wsrc = wsrc < 0 ? -wsrc : (wsrc > 8191 ? 16382 - wsrc : wsrc);
      const uint4 d = *(const uint4*)(qkvt + ((size_t)((b << 13) + wsrc)) * 832 + 512 + (h << 6) + (half << 5) + (u << 3));
      *(uint4*)(sb + (row << 5) + (((u + (row >> 1)) & 3) << 3)) = d;
    }
    __syncthreads();
#pragma unroll
    for (int jj = 0; jj < 4; ++jj){
      float o[8] = {0.f,0.f,0.f,0.f,0.f,0.f,0.f,0.f};
#pragma unroll
      for (int kk = 0; kk < 7; ++kk){
        const int r = t + kk;
        const uint4 vv = *(const uint4*)(sb + (r << 5) + (((jj + (r >> 1)) & 3) << 3));
        const float pk = p[kk];
        o[0] += pk * b2f_lo(vv.x); o[1] += pk * b2f_hi(vv.x);
        o[2] += pk * b2f_lo(vv.y); o[3] += pk * b2f_hi(vv.y);
        o[4] += pk * b2f_lo(vv.z); o[5] += pk * b2f_hi(vv.z);
        o[6] += pk * b2f_lo(vv.w); o[7] += pk * b2f_hi(vv.w);
      }
      const int dl0 = (half << 5) + (jj << 3);
#pragma unroll
      for (int e = 0; e < 8; ++e){
        const int dl = dl0 + e;
        const float oc = depw[(h << 6) + dl] * fv[dl >> 2] + depb[(h << 6) + dl];
        out[(((size_t)((b << 8) + (h << 6) + dl)) << 13) + w] = r1 * o[e] + r2 * oc;
      }
    }
  }
}

// ---------------------------------------------------------------------------
// launch
// ---------------------------------------------------------------------------
extern "C" void kernel_launch(void* const* d_in, const int* in_sizes, int n_in,
                              void* d_out, int out_size, void* d_ws, size_t ws_size,
                              hipStream_t stream){
  (void)in_sizes; (void)n_in; (void)out_size; (void)ws_size;
  const float* x    = (const float*)d_in[0];
  const float* w1   = (const float*)d_in[1];
  const float* b1   = (const float*)d_in[2];
  const float* w2   = (const float*)d_in[3];
  const float* b2   = (const float*)d_in[4];
  const float* w3   = (const float*)d_in[5];
  const float* b3   = (const float*)d_in[6];
  const float* wp   = (const float*)d_in[7];
  // d_in[8] = bp : cancels analytically (pe - unfolded pe), unused
  const float* fcw  = (const float*)d_in[9];
  const float* depw = (const float*)d_in[10];
  const float* depb = (const float*)d_in[11];
  const float* r1p  = (const float*)d_in[12];
  const float* r2p  = (const float*)d_in[13];
  float* out = (float*)d_out;

  char* ws = (char*)d_ws;
  u16*   xt   = (u16*)(ws);                    // 4*8192*256*2   = 16,777,216 B
  u16*   Wall = (u16*)(ws + 16777216);         // 896*256*2      =    458,752 B
  float* ball = (float*)(ws + 17235968);       // 896*4          =      3,584 B
  u16*   qkvt = (u16*)(ws + 17239552);         // 4*8192*832*2   = 54,525,952 B
                                               // total ~71.8 MB

  k_transpose<<<dim3(128, 4, 4), 256, 0, stream>>>(x, xt);
  k_build<<<dim3(896, 1, 1), 256, 0, stream>>>(w1, b1, w2, b2, w3, b3, fcw, Wall, ball);
  gemm_qkv<<<dim3(1792, 1, 1), 256, 0, stream>>>(Wall, ball, xt, qkvt);
  attn_out<<<dim3(32, 4, 4), 256, 0, stream>>>(qkvt, wp, depw, depb, r1p, r2p, out);
}

// Round 2
// 217.641 us; speedup vs baseline: 1.0573x; 1.0063x over previous
//
#include <hip/hip_runtime.h>
#include <stdint.h>
#include <stddef.h>

typedef unsigned short u16;
typedef unsigned int   u32;

typedef __attribute__((ext_vector_type(8))) short bf16x8;
typedef __attribute__((ext_vector_type(4))) float f32x4;

__device__ __forceinline__ float b2f(u16 u)    { return __uint_as_float(((u32)u) << 16); }
__device__ __forceinline__ float b2f_lo(u32 v) { return __uint_as_float(v << 16); }
__device__ __forceinline__ float b2f_hi(u32 v) { return __uint_as_float(v & 0xFFFF0000u); }
__device__ __forceinline__ u16 f2b(float f){
  u32 x = __float_as_uint(f);
  return (u16)((x + 0x7FFFu + ((x >> 16) & 1u)) >> 16);
}

// qkv7 layout: per-m-tile dense buffers.
//   mt = 0..5 : [b][w][128] u16, base = mt * 4194304 (u16 units)
//   mt = 6    : [b][w][64]  u16 (f rows 768..831), base = 25165824
// total 27,262,976 u16 = 54,525,952 B (identical footprint to old qkvt).
#define MT_STRIDE 4194304u
#define F_BASE    25165824u

// ---------------------------------------------------------------------------
// K0a: x[b][c][w] FLOAT32 -> xt[b][w][c] bf16 (fused transpose+downconvert).
// ---------------------------------------------------------------------------
__global__ __launch_bounds__(256) void k_transpose(const float* __restrict__ x, u16* __restrict__ xt){
  __shared__ u16 tile[64 * 65];
  const int wt = blockIdx.x, ct = blockIdx.y, b = blockIdx.z;
  const int W0 = wt << 6, C0 = ct << 6;
  const int t = threadIdx.x;
#pragma unroll
  for (int it = 0; it < 4; ++it){
    const int task = t + (it << 8);          // 0..1023
    const int c = task >> 4, u = task & 15;  // c<64, u<16 (float4 chunks of 64-wide row)
    const float4 d = *(const float4*)(x + ((size_t)((b << 8) + C0 + c) << 13) + W0 + (u << 2));
    const int base = c * 65 + (u << 2);
    tile[base + 0] = f2b(d.x); tile[base + 1] = f2b(d.y);
    tile[base + 2] = f2b(d.z); tile[base + 3] = f2b(d.w);
  }
  __syncthreads();
#pragma unroll
  for (int it = 0; it < 2; ++it){
    const int task = t + (it << 8);          // 0..511
    const int wr = task >> 3, cu = task & 7; // wr<64, cu<8 (8 bf16 per chunk)
    const int cb = cu << 3;
    u32 a0 = (u32)tile[(cb + 0) * 65 + wr] | ((u32)tile[(cb + 1) * 65 + wr] << 16);
    u32 a1 = (u32)tile[(cb + 2) * 65 + wr] | ((u32)tile[(cb + 3) * 65 + wr] << 16);
    u32 a2 = (u32)tile[(cb + 4) * 65 + wr] | ((u32)tile[(cb + 5) * 65 + wr] << 16);
    u32 a3 = (u32)tile[(cb + 6) * 65 + wr] | ((u32)tile[(cb + 7) * 65 + wr] << 16);
    uint4 val = make_uint4(a0, a1, a2, a3);
    *(uint4*)(xt + ((size_t)((b << 13) + W0 + wr) << 8) + C0 + cb) = val;
  }
}

// ---------------------------------------------------------------------------
// K0b: build combined weight matrix Wall[896][256] (bf16) + fp32 bias ball[896].
// rows 0-255: w1/b1, 256-511: w2/b2, 512-767: w3/b3, 768-831: fc-folded, rest 0.
// ---------------------------------------------------------------------------
__global__ __launch_bounds__(256) void k_build(const float* __restrict__ w1, const float* __restrict__ b1,
                                               const float* __restrict__ w2, const float* __restrict__ b2,
                                               const float* __restrict__ w3, const float* __restrict__ b3,
                                               const float* __restrict__ fcw,
                                               u16* __restrict__ Wall, float* __restrict__ ball){
  const int r = blockIdx.x, c = threadIdx.x;
  float v = 0.f, bv = 0.f;
  if (r < 256){      v = w1[(r << 8) + c];          bv = b1[r]; }
  else if (r < 512){ v = w2[((r - 256) << 8) + c];  bv = b2[r - 256]; }
  else if (r < 768){ v = w3[((r - 512) << 8) + c];  bv = b3[r - 512]; }
  else if (r < 832){
    const int d = r - 768;
    float s = 0.f, sbias = 0.f;
#pragma unroll
    for (int h = 0; h < 4; ++h){
      const int ch = (h << 6) + d;
      const float f1 = fcw[h], f2 = fcw[4 + h], f3 = fcw[8 + h];
      s     += f1 * w1[(ch << 8) + c] + f2 * w2[(ch << 8) + c] + f3 * w3[(ch << 8) + c];
      sbias += f1 * b1[ch] + f2 * b2[ch] + f3 * b3[ch];
    }
    v = s; bv = sbias;
  }
  Wall[(r << 8) + c] = f2b(v);
  if (c == 0) ball[r] = bv;
}

// ---------------------------------------------------------------------------
// K1: GEMM  qkv7[mt][b][w][ml] = Wall[m][:] . xt[b][w][:] + ball[m].
// M=896 (7 tiles of 128), N=32768 (b,w; 128-col tiles), K=256 (BK=64).
// XCD-grouped 1-D grid (one nt's 7 mt-blocks share an XCD's L2).
// XOR-swizzled As/Bs; register prefetch of next K-tile.
// Epilogue: bias + bf16 pack -> LDS transpose -> DENSE per-mt output buffer:
// each block writes one fully-contiguous 32 KB region (16 KB for mt=6).
// grid 1792 x 256 threads.
// ---------------------------------------------------------------------------
__global__ __launch_bounds__(256) void gemm_qkv(const u16* __restrict__ Wall, const float* __restrict__ ball,
                                                const u16* __restrict__ xt, u16* __restrict__ qkv7){
  __shared__ __align__(16) u16 sm[2 * 128 * 64];   // As | Bs, reused as 128x128 C-tile
  u16* As = sm;
  u16* Bs = sm + 128 * 64;

  const int bid = blockIdx.x;
  const int w_id = ((bid & 7) * 224) + (bid >> 3);  // 0..1791, bijective
  const int mt = w_id % 7;
  const int nt = w_id / 7;                          // 0..255
  const int b = nt >> 6;
  const int w0 = (nt & 63) << 7;
  const int tid = threadIdx.x;
  const int wave = tid >> 6, lane = tid & 63;
  const int wy = wave >> 1, wx = wave & 1;
  const int m0 = mt << 7;
  const int quad = lane >> 4, l15 = lane & 15;
  f32x4 acc[4][4] = {};

  uint4 ra[4], rb[4];
  auto stage_load = [&](int kc){
#pragma unroll
    for (int k = 0; k < 4; ++k){
      const int cid = tid + (k << 8);          // 0..1023
      const int row = cid >> 3, u = cid & 7;   // row<128, unit<8 (8 bf16 each)
      ra[k] = *(const uint4*)(Wall + ((m0 + row) << 8) + kc + (u << 3));
      rb[k] = *(const uint4*)(xt + (((size_t)((b << 13) + w0 + row)) << 8) + kc + (u << 3));
    }
  };

  stage_load(0);
#pragma unroll
  for (int kt = 0; kt < 4; ++kt){
    __syncthreads();   // previous iteration's LDS reads complete before overwrite
#pragma unroll
    for (int k = 0; k < 4; ++k){
      const int cid = tid + (k << 8);
      const int row = cid >> 3, u = (cid & 7) ^ (row & 7);   // T2 XOR swizzle
      *(uint4*)(As + (row << 6) + (u << 3)) = ra[k];
      *(uint4*)(Bs + (row << 6) + (u << 3)) = rb[k];
    }
    __syncthreads();
    if (kt < 3) stage_load((kt + 1) << 6);     // prefetch next tile under compute
#pragma unroll
    for (int ks = 0; ks < 2; ++ks){
      bf16x8 av[4], bvv[4];
#pragma unroll
      for (int i = 0; i < 4; ++i){
        const int rowA = (wy << 6) + (i << 4) + l15;
        const int ca = ((ks << 2) + quad) ^ (rowA & 7);
        av[i] = *(const bf16x8*)(As + (rowA << 6) + (ca << 3));
        const int rowB = (wx << 6) + (i << 4) + l15;
        const int cb2 = ((ks << 2) + quad) ^ (rowB & 7);
        bvv[i] = *(const bf16x8*)(Bs + (rowB << 6) + (cb2 << 3));
      }
#pragma unroll
      for (int i = 0; i < 4; ++i)
#pragma unroll
        for (int j = 0; j < 4; ++j)
          acc[i][j] = __builtin_amdgcn_mfma_f32_16x16x32_bf16(av[i], bvv[j], acc[i][j], 0, 0, 0);
    }
  }

  // --- epilogue: bias + bf16 pack into LDS as [w_local][m_local] (swizzled),
  //     then 16 B/thread stores into the DENSE per-mt buffer. ---
  __syncthreads();   // all waves done reading As/Bs
#pragma unroll
  for (int i = 0; i < 4; ++i){
    const int ml = (wy << 6) + (i << 4) + (quad << 2);      // 4 consecutive m
    const float4 bias = *(const float4*)(ball + m0 + ml);
#pragma unroll
    for (int j = 0; j < 4; ++j){
      const int wl = (wx << 6) + (j << 4) + l15;
      f32x4 r = acc[i][j];
      uint2 val;
      val.x = (u32)f2b(r.x + bias.x) | ((u32)f2b(r.y + bias.y) << 16);
      val.y = (u32)f2b(r.z + bias.z) | ((u32)f2b(r.w + bias.w) << 16);
      const int byte = ((wl << 8) + (ml << 1)) ^ ((wl & 7) << 4);
      *(uint2*)((char*)sm + byte) = val;
    }
  }
  __syncthreads();
#pragma unroll
  for (int it = 0; it < 8; ++it){
    const int task = tid + (it << 8);        // 0..2047
    const int wl = task >> 4, c = task & 15; // wl<128, 16B chunk c<16
    const int byte = ((wl << 8) + (c << 4)) ^ ((wl & 7) << 4);
    const uint4 val = *(const uint4*)((const char*)sm + byte);
    const size_t row = (size_t)((b << 13) + w0 + wl);
    if (mt < 6){
      *(uint4*)(qkv7 + (size_t)mt * MT_STRIDE + (row << 7) + (c << 3)) = val;
    } else if (c < 8){
      *(uint4*)(qkv7 + (size_t)F_BASE + (row << 6) + (c << 3)) = val;
    }
  }
}

// ---------------------------------------------------------------------------
// K2: windowed attention (K_ATT=7, reflect pad) + folded conv branch + combine.
// One thread per (b,h,w).  grid (32 wtiles of 256, 4 heads, 4 b) x 256 threads.
// Reads q/k/v/f from the dense per-mt buffers (row strides 256/256/256/128 B).
// ---------------------------------------------------------------------------
__global__ __launch_bounds__(256) void attn_out(const u16* __restrict__ qkv7, const float* __restrict__ wp,
                                                const float* __restrict__ depw, const float* __restrict__ depb,
                                                const float* __restrict__ r1p, const float* __restrict__ r2p,
                                                float* __restrict__ out){
  __shared__ __align__(16) u16 sb[262 * 32];
  __shared__ float wpL[64];
  const int wt = blockIdx.x, h = blockIdx.y, b = blockIdx.z;
  const int w0 = wt << 8;
  const int t = threadIdx.x;
  const int w = w0 + t;
  if (t < 64) wpL[t] = wp[t];

  const int hcol = (h & 1) << 6;     // column offset of this head inside a 128-wide tile
  const int hsel = h >> 1;           // which of the two tiles per component

  // q: mt = hsel, cols hcol..hcol+63
  const u16* qbase = qkv7 + (size_t)hsel * MT_STRIDE + (((size_t)((b << 13) + w)) << 7) + hcol;
  uint4 qreg[8];
#pragma unroll
  for (int j = 0; j < 8; ++j) qreg[j] = *(const uint4*)(qbase + (j << 3));

  // f: half-width tile, cols h*16..h*16+15
  float fv[16];
  {
    const u16* fbase = qkv7 + (size_t)F_BASE + (((size_t)((b << 13) + w)) << 6) + (h << 4);
    uint4 f0 = *(const uint4*)(fbase);
    uint4 f1 = *(const uint4*)(fbase + 8);
    fv[0] = b2f_lo(f0.x); fv[1] = b2f_hi(f0.x); fv[2]  = b2f_lo(f0.y); fv[3]  = b2f_hi(f0.y);
    fv[4] = b2f_lo(f0.z); fv[5] = b2f_hi(f0.z); fv[6]  = b2f_lo(f0.w); fv[7]  = b2f_hi(f0.w);
    fv[8] = b2f_lo(f1.x); fv[9] = b2f_hi(f1.x); fv[10] = b2f_lo(f1.y); fv[11] = b2f_hi(f1.y);
    fv[12]= b2f_lo(f1.z); fv[13]= b2f_hi(f1.z); fv[14] = b2f_lo(f1.w); fv[15] = b2f_hi(f1.w);
  }

  float att[7] = {0.f,0.f,0.f,0.f,0.f,0.f,0.f};
  float qd = 0.f;

  // --- phase A: att[kk] = q . k[w+kk-3]  (two 32-channel halves) ---
#pragma unroll
  for (int half = 0; half < 2; ++half){
    const u16* kbase = qkv7 + (size_t)(2 + hsel) * MT_STRIDE + hcol + (half << 5);
    __syncthreads();
    for (int idx = t; idx < 262 * 4; idx += 256){
      const int row = idx >> 2, u = idx & 3;
      int wsrc = w0 - 3 + row;
      wsrc = wsrc < 0 ? -wsrc : (wsrc > 8191 ? 16382 - wsrc : wsrc);
      const uint4 d = *(const uint4*)(kbase + (((size_t)((b << 13) + wsrc)) << 7) + (u << 3));
      *(uint4*)(sb + (row << 5) + (((u + (row >> 1)) & 3) << 3)) = d;
    }
    __syncthreads();
#pragma unroll
    for (int jj = 0; jj < 4; ++jj){
      const int j = (half << 2) + jj;
      float qf[8];
      {
        const uint4 q4 = qreg[j];
        qf[0] = b2f_lo(q4.x); qf[1] = b2f_hi(q4.x); qf[2] = b2f_lo(q4.y); qf[3] = b2f_hi(q4.y);
        qf[4] = b2f_lo(q4.z); qf[5] = b2f_hi(q4.z); qf[6] = b2f_lo(q4.w); qf[7] = b2f_hi(q4.w);
      }
#pragma unroll
      for (int e = 0; e < 8; ++e) qd += qf[e] * wpL[(j << 3) + e];
#pragma unroll
      for (int kk = 0; kk < 7; ++kk){
        const int r = t + kk;
        const uint4 kv = *(const uint4*)(sb + (r << 5) + (((jj + (r >> 1)) & 3) << 3));
        float a = att[kk];
        a += qf[0] * b2f_lo(kv.x) + qf[1] * b2f_hi(kv.x) + qf[2] * b2f_lo(kv.y) + qf[3] * b2f_hi(kv.y)
           + qf[4] * b2f_lo(kv.z) + qf[5] * b2f_hi(kv.z) + qf[6] * b2f_lo(kv.w) + qf[7] * b2f_hi(kv.w);
        att[kk] = a;
      }
    }
  }

  // --- positional term + scale + softmax over the 7-window ---
  const float locw = -1.f + (2.f / 8191.f) * (float)w;
  float mx = -1e30f;
#pragma unroll
  for (int kk = 0; kk < 7; ++kk){
    int wr = w + kk - 3;
    wr = wr < 0 ? -wr : (wr > 8191 ? 16382 - wr : wr);
    const float lr = -1.f + (2.f / 8191.f) * (float)wr;
    att[kk] = 0.125f * (att[kk] + (locw - lr) * qd);
    mx = fmaxf(mx, att[kk]);
  }
  float p[7]; float ssum = 0.f;
#pragma unroll
  for (int kk = 0; kk < 7; ++kk){ p[kk] = __expf(att[kk] - mx); ssum += p[kk]; }
  const float inv = 1.f / ssum;
#pragma unroll
  for (int kk = 0; kk < 7; ++kk) p[kk] *= inv;

  const float r1 = r1p[0];
  const float r2 = r2p[0];

  // --- phase B: out = rate1 * (P.V) + rate2 * (dep_w * f + dep_b) ---
#pragma unroll
  for (int half = 0; half < 2; ++half){
    const u16* vbase = qkv7 + (size_t)(4 + hsel) * MT_STRIDE + hcol + (half << 5);
    __syncthreads();
    for (int idx = t; idx < 262 * 4; idx += 256){
      const int row = idx >> 2, u = idx & 3;
      int wsrc = w0 - 3 + row;
      wsrc = wsrc < 0 ? -wsrc : (wsrc > 8191 ? 16382 - wsrc : wsrc);
      const uint4 d = *(const uint4*)(vbase + (((size_t)((b << 13) + wsrc)) << 7) + (u << 3));
      *(uint4*)(sb + (row << 5) + (((u + (row >> 1)) & 3) << 3)) = d;
    }
    __syncthreads();
#pragma unroll
    for (int jj = 0; jj < 4; ++jj){
      float o[8] = {0.f,0.f,0.f,0.f,0.f,0.f,0.f,0.f};
#pragma unroll
      for (int kk = 0; kk < 7; ++kk){
        const int r = t + kk;
        const uint4 vv = *(const uint4*)(sb + (r << 5) + (((jj + (r >> 1)) & 3) << 3));
        const float pk = p[kk];
        o[0] += pk * b2f_lo(vv.x); o[1] += pk * b2f_hi(vv.x);
        o[2] += pk * b2f_lo(vv.y); o[3] += pk * b2f_hi(vv.y);
        o[4] += pk * b2f_lo(vv.z); o[5] += pk * b2f_hi(vv.z);
        o[6] += pk * b2f_lo(vv.w); o[7] += pk * b2f_hi(vv.w);
      }
      const int dl0 = (half << 5) + (jj << 3);
#pragma unroll
      for (int e = 0; e < 8; ++e){
        const int dl = dl0 + e;
        const float oc = depw[(h << 6) + dl] * fv[dl >> 2] + depb[(h << 6) + dl];
        out[(((size_t)((b << 8) + (h << 6) + dl)) << 13) + w] = r1 * o[e] + r2 * oc;
      }
    }
  }
}

// ---------------------------------------------------------------------------
// launch
// ---------------------------------------------------------------------------
extern "C" void kernel_launch(void* const* d_in, const int* in_sizes, int n_in,
                              void* d_out, int out_size, void* d_ws, size_t ws_size,
                              hipStream_t stream){
  (void)in_sizes; (void)n_in; (void)out_size; (void)ws_size;
  const float* x    = (const float*)d_in[0];
  const float* w1   = (const float*)d_in[1];
  const float* b1   = (const float*)d_in[2];
  const float* w2   = (const float*)d_in[3];
  const float* b2   = (const float*)d_in[4];
  const float* w3   = (const float*)d_in[5];
  const float* b3   = (const float*)d_in[6];
  const float* wp   = (const float*)d_in[7];
  // d_in[8] = bp : cancels analytically (pe - unfolded pe), unused
  const float* fcw  = (const float*)d_in[9];
  const float* depw = (const float*)d_in[10];
  const float* depb = (const float*)d_in[11];
  const float* r1p  = (const float*)d_in[12];
  const float* r2p  = (const float*)d_in[13];
  float* out = (float*)d_out;

  char* ws = (char*)d_ws;
  u16*   xt   = (u16*)(ws);                    // 4*8192*256*2   = 16,777,216 B
  u16*   Wall = (u16*)(ws + 16777216);         // 896*256*2      =    458,752 B
  float* ball = (float*)(ws + 17235968);       // 896*4          =      3,584 B
  u16*   qkv7 = (u16*)(ws + 17239552);         // 54,525,952 B (dense per-mt tiles)
                                               // total ~71.8 MB (unchanged)

  k_transpose<<<dim3(128, 4, 4), 256, 0, stream>>>(x, xt);
  k_build<<<dim3(896, 1, 1), 256, 0, stream>>>(w1, b1, w2, b2, w3, b3, fcw, Wall, ball);
  gemm_qkv<<<dim3(1792, 1, 1), 256, 0, stream>>>(Wall, ball, xt, qkv7);
  attn_out<<<dim3(32, 4, 4), 256, 0, stream>>>(qkv7, wp, depw, depb, r1p, r2p, out);
}

// Round 5
// 214.687 us; speedup vs baseline: 1.0719x; 1.0138x over previous
//
#include <hip/hip_runtime.h>
#include <stdint.h>
#include <stddef.h>

typedef unsigned short u16;
typedef unsigned int   u32;

typedef __attribute__((ext_vector_type(8))) short bf16x8;
typedef __attribute__((ext_vector_type(4))) float f32x4;

__device__ __forceinline__ float b2f_lo(u32 v) { return __uint_as_float(v << 16); }
__device__ __forceinline__ float b2f_hi(u32 v) { return __uint_as_float(v & 0xFFFF0000u); }
__device__ __forceinline__ u16 f2b(float f){
  u32 x = __float_as_uint(f);
  return (u16)((x + 0x7FFFu + ((x >> 16) & 1u)) >> 16);
}
__device__ __forceinline__ int refl(int w){ return w < 0 ? -w : (w > 8191 ? 16382 - w : w); }
__device__ __forceinline__ void up8(const uint4 v, float* f){
  f[0] = b2f_lo(v.x); f[1] = b2f_hi(v.x); f[2] = b2f_lo(v.y); f[3] = b2f_hi(v.y);
  f[4] = b2f_lo(v.z); f[5] = b2f_hi(v.z); f[6] = b2f_lo(v.w); f[7] = b2f_hi(v.w);
}

// ---------------------------------------------------------------------------
// K0: build combined weight matrix Wall[896][256] (bf16) + fp32 bias ball[896].
// rows 0-255: w1/b1, 256-511: w2/b2, 512-767: w3/b3, 768-831: fc-folded, rest 0.
// ---------------------------------------------------------------------------
__global__ __launch_bounds__(256) void k_build(const float* __restrict__ w1, const float* __restrict__ b1,
                                               const float* __restrict__ w2, const float* __restrict__ b2,
                                               const float* __restrict__ w3, const float* __restrict__ b3,
                                               const float* __restrict__ fcw,
                                               u16* __restrict__ Wall, float* __restrict__ ball){
  const int r = blockIdx.x, c = threadIdx.x;
  float v = 0.f, bv = 0.f;
  if (r < 256){      v = w1[(r << 8) + c];          bv = b1[r]; }
  else if (r < 512){ v = w2[((r - 256) << 8) + c];  bv = b2[r - 256]; }
  else if (r < 768){ v = w3[((r - 512) << 8) + c];  bv = b3[r - 512]; }
  else if (r < 832){
    const int d = r - 768;
    float s = 0.f, sbias = 0.f;
#pragma unroll
    for (int h = 0; h < 4; ++h){
      const int ch = (h << 6) + d;
      const float f1 = fcw[h], f2 = fcw[4 + h], f3 = fcw[8 + h];
      s     += f1 * w1[(ch << 8) + c] + f2 * w2[(ch << 8) + c] + f3 * w3[(ch << 8) + c];
      sbias += f1 * b1[ch] + f2 * b2[ch] + f3 * b3[ch];
    }
    v = s; bv = sbias;
  }
  Wall[(r << 8) + c] = f2b(v);
  if (c == 0) ball[r] = bv;
}

// ---------------------------------------------------------------------------
// K1 (fused): per (b, 64-w stripe): transpose-stage x -> LDS bf16, 7 tile-GEMMs
// (qkvf) into LDS, windowed attention + dep-conv + combine, store out.
// qkv intermediates never touch HBM.
//
// LDS map (bytes):
//   Bl  [80 r][256 k] bf16, chunk ^= (r&31)        40960   (r <-> w0-4+r)
//   As  [128 m][64 k] bf16, chunk ^= (row&7)       16384   (aliased by f tile)
//   Ql  [64 wl][256 ch] bf16, chunk ^= (wl&31)     32768
//   KVl [70 rr][512 ch] bf16, chunk ^= (rr&31)     71680   (rr <-> w0-3+rr; k=0..255, v=256..511)
//   wpL 64 f32                                       256
//   total 162048 B (158.25 KiB) -> 1 block/CU, grid 512 = 2 rounds of 256 CUs.
// ---------------------------------------------------------------------------
__global__ __launch_bounds__(256, 1) void fused_acmix(
    const u16* __restrict__ Wall, const float* __restrict__ ball,
    const float* __restrict__ x, const float* __restrict__ wp,
    const float* __restrict__ depw, const float* __restrict__ depb,
    const float* __restrict__ r1p, const float* __restrict__ r2p,
    float* __restrict__ out)
{
  __shared__ __align__(16) u16 Bl [80 * 256];
  __shared__ __align__(16) u16 As [128 * 64];
  __shared__ __align__(16) u16 Ql [64 * 256];
  __shared__ __align__(16) u16 KVl[70 * 512];
  __shared__ float wpL[64];
  u16* Fl = As;   // f tile aliases As after the last GEMM (guarded by barrier)

  const int bid = blockIdx.x;
  const int w_id = ((bid & 7) << 6) + (bid >> 3);  // XCD-contiguous stripes (512 = 8*64)
  const int b = w_id >> 7;                          // 0..3
  const int stripe = w_id & 127;                    // 0..127
  const int w0 = stripe << 6;

  const int t = threadIdx.x;
  const int wv = t >> 6, lane = t & 63;
  const int quad = lane >> 4, l15 = lane & 15;

  if (t < 64) wpL[t] = wp[t];

  // ---- stage Bl: x[b][ch][w] -> Bl[r][ch] bf16, r <-> w = refl(w0-4+r) ----
  {
    const float* xb = x + ((size_t)b << 21);        // b*256*8192
    const int cg = wv;                              // wave owns cc = cg, cg+4, ...
    const int rl = lane;
#pragma unroll
    for (int ci = 0; ci < 8; ++ci){
      const int cc = cg + (ci << 2);                // 0..31 (16B chunk = 8 channels)
#pragma unroll
      for (int rb = 0; rb < 2; ++rb){
        const int r = rl + (rb << 6);
        if (r < 80){
          const int w = refl(w0 - 4 + r);
          u32 pk0, pk1, pk2, pk3;
          {
            const size_t base = ((size_t)(cc << 3)) << 13;
            const float f0 = xb[base + (0u << 13) + w];
            const float f1 = xb[base + (1u << 13) + w];
            const float f2 = xb[base + (2u << 13) + w];
            const float f3 = xb[base + (3u << 13) + w];
            const float f4 = xb[base + (4u << 13) + w];
            const float f5 = xb[base + (5u << 13) + w];
            const float f6 = xb[base + (6u << 13) + w];
            const float f7 = xb[base + (7u << 13) + w];
            pk0 = (u32)f2b(f0) | ((u32)f2b(f1) << 16);
            pk1 = (u32)f2b(f2) | ((u32)f2b(f3) << 16);
            pk2 = (u32)f2b(f4) | ((u32)f2b(f5) << 16);
            pk3 = (u32)f2b(f6) | ((u32)f2b(f7) << 16);
          }
          *(uint4*)((char*)Bl + r * 512 + ((cc ^ (r & 31)) << 4)) = make_uint4(pk0, pk1, pk2, pk3);
        }
      }
    }
  }

  // ---- GEMM phase: 7 mt tiles (q q k k v v f), K=256 in 4 chunks of 64 ----
  uint4 ra[4];
  auto loadA = [&](int mt_, int kc_){
#pragma unroll
    for (int k4 = 0; k4 < 4; ++k4){
      const int task = t + (k4 << 8);               // 0..1023
      const int row = task >> 3, u = task & 7;
      ra[k4] = *(const uint4*)(Wall + (((mt_ << 7) + row) << 8) + (kc_ << 6) + (u << 3));
    }
  };
  loadA(0, 0);

#pragma unroll
  for (int mt = 0; mt < 7; ++mt){
    f32x4 acc[2][5] = {};
#pragma unroll
    for (int kc = 0; kc < 4; ++kc){
      __syncthreads();                              // As safe to overwrite (also fences Bl on iter 0)
#pragma unroll
      for (int k4 = 0; k4 < 4; ++k4){
        const int task = t + (k4 << 8);
        const int row = task >> 3, u = (task & 7) ^ (row & 7);
        *(uint4*)((char*)As + row * 128 + (u << 4)) = ra[k4];
      }
      __syncthreads();
      {
        const int idx = (mt << 2) + kc;
        if (idx < 27) loadA((idx + 1) >> 2, (idx + 1) & 3);  // prefetch next A-tile under MFMA
      }
#pragma unroll
      for (int ks = 0; ks < 2; ++ks){
        bf16x8 av[2], bv[5];
#pragma unroll
        for (int i = 0; i < 2; ++i){
          const int rowA = (wv << 5) + (i << 4) + l15;
          const int ca = ((ks << 2) + quad) ^ (rowA & 7);
          av[i] = *(const bf16x8*)((const char*)As + rowA * 128 + (ca << 4));
        }
#pragma unroll
        for (int j = 0; j < 5; ++j){
          const int rowB = (j << 4) + l15;
          const int cb = ((kc << 3) + (ks << 2) + quad) ^ (rowB & 31);
          bv[j] = *(const bf16x8*)((const char*)Bl + rowB * 512 + (cb << 4));
        }
#pragma unroll
        for (int i = 0; i < 2; ++i)
#pragma unroll
          for (int j = 0; j < 5; ++j)
            acc[i][j] = __builtin_amdgcn_mfma_f32_16x16x32_bf16(av[i], bv[j], acc[i][j], 0, 0, 0);
      }
    }

    // epilogue: C[m = wv*32+i*16+quad*4+reg][r = j*16+l15] -> route to LDS
    if (mt == 6) __syncthreads();                   // all As reads done before f-alias writes
#pragma unroll
    for (int i = 0; i < 2; ++i){
      const int mloc = (wv << 5) + (i << 4) + (quad << 2);
      const float4 bias = *(const float4*)(ball + (mt << 7) + mloc);
#pragma unroll
      for (int j = 0; j < 5; ++j){
        const int r = (j << 4) + l15;
        f32x4 c = acc[i][j];
        uint2 val;
        val.x = (u32)f2b(c.x + bias.x) | ((u32)f2b(c.y + bias.y) << 16);
        val.y = (u32)f2b(c.z + bias.z) | ((u32)f2b(c.w + bias.w) << 16);
        if (mt < 2){
          const int wl = r - 4;                     // q: center rows only
          if ((unsigned)wl < 64u){
            const int chunk = ((mt << 7) + mloc) >> 3;
            *(uint2*)((char*)Ql + wl * 512 + ((chunk ^ (wl & 31)) << 4) + ((quad & 1) << 3)) = val;
          }
        } else if (mt < 6){
          const int rr = r - 1;                     // k/v: 70 halo rows
          if ((unsigned)rr < 70u){
            const int chunk = (((mt - 2) << 7) + mloc) >> 3;   // k: 0..31, v: 32..63
            *(uint2*)((char*)KVl + rr * 1024 + ((chunk ^ (rr & 31)) << 4) + ((quad & 1) << 3)) = val;
          }
        } else {
          const int wl = r - 4;                     // f: center rows, first 64 m only
          if ((unsigned)wl < 64u && mloc < 64){
            const int chunk = mloc >> 3;            // 0..7
            *(uint2*)((char*)Fl + wl * 128 + ((chunk ^ (wl & 7)) << 4) + ((quad & 1) << 3)) = val;
          }
        }
      }
    }
  }
  __syncthreads();

  // ---- attention phase: thread = (h = t>>6, wl = t&63), w = w0+wl ----
  const int h = t >> 6, wl = t & 63;
  const int w = w0 + wl;

  float att[7] = {0.f,0.f,0.f,0.f,0.f,0.f,0.f};
  float qd = 0.f;
#pragma unroll
  for (int e = 0; e < 8; ++e){
    const int cq = (h << 3) + e;
    const uint4 q4 = *(const uint4*)((const char*)Ql + wl * 512 + ((cq ^ (wl & 31)) << 4));
    float qf[8]; up8(q4, qf);
#pragma unroll
    for (int d = 0; d < 8; ++d) qd += qf[d] * wpL[(e << 3) + d];
#pragma unroll
    for (int kk = 0; kk < 7; ++kk){
      const int rr = wl + kk;                       // w0-3+wl+kk
      const uint4 k4 = *(const uint4*)((const char*)KVl + rr * 1024 + ((((h << 3) + e) ^ (rr & 31)) << 4));
      float kf[8]; up8(k4, kf);
      att[kk] += qf[0]*kf[0] + qf[1]*kf[1] + qf[2]*kf[2] + qf[3]*kf[3]
               + qf[4]*kf[4] + qf[5]*kf[5] + qf[6]*kf[6] + qf[7]*kf[7];
    }
  }

  // positional term + scale + softmax
  const float locw = -1.f + (2.f / 8191.f) * (float)w;
  float mx = -1e30f;
#pragma unroll
  for (int kk = 0; kk < 7; ++kk){
    const int wr = refl(w + kk - 3);
    const float lr = -1.f + (2.f / 8191.f) * (float)wr;
    att[kk] = 0.125f * (att[kk] + (locw - lr) * qd);
    mx = fmaxf(mx, att[kk]);
  }
  float p[7]; float ssum = 0.f;
#pragma unroll
  for (int kk = 0; kk < 7; ++kk){ p[kk] = __expf(att[kk] - mx); ssum += p[kk]; }
  const float inv = 1.f / ssum;
#pragma unroll
  for (int kk = 0; kk < 7; ++kk) p[kk] *= inv;

  // f values for dep-conv (16 per head)
  float fvv[16];
  {
    const int c0 = h << 1;
    const uint4 f0 = *(const uint4*)((const char*)Fl + wl * 128 + ((c0 ^ (wl & 7)) << 4));
    const uint4 f1 = *(const uint4*)((const char*)Fl + wl * 128 + (((c0 + 1) ^ (wl & 7)) << 4));
    up8(f0, fvv); up8(f1, fvv + 8);
  }

  const float r1 = r1p[0];
  const float r2 = r2p[0];

  // PV + dep-conv + combine + store
#pragma unroll
  for (int e = 0; e < 8; ++e){
    float o8[8] = {0.f,0.f,0.f,0.f,0.f,0.f,0.f,0.f};
#pragma unroll
    for (int kk = 0; kk < 7; ++kk){
      const int rr = wl + kk;
      const uint4 v4 = *(const uint4*)((const char*)KVl + rr * 1024 + (((32 + (h << 3) + e) ^ (rr & 31)) << 4));
      float vf[8]; up8(v4, vf);
      const float pk = p[kk];
      o8[0] += pk * vf[0]; o8[1] += pk * vf[1]; o8[2] += pk * vf[2]; o8[3] += pk * vf[3];
      o8[4] += pk * vf[4]; o8[5] += pk * vf[5]; o8[6] += pk * vf[6]; o8[7] += pk * vf[7];
    }
#pragma unroll
    for (int s = 0; s < 8; ++s){
      const int dl = (e << 3) + s;
      const float oc = depw[(h << 6) + dl] * fvv[dl >> 2] + depb[(h << 6) + dl];
      out[(((size_t)((b << 8) + (h << 6) + dl)) << 13) + w] = r1 * o8[s] + r2 * oc;
    }
  }
}

// ---------------------------------------------------------------------------
// launch
// ---------------------------------------------------------------------------
extern "C" void kernel_launch(void* const* d_in, const int* in_sizes, int n_in,
                              void* d_out, int out_size, void* d_ws, size_t ws_size,
                              hipStream_t stream){
  (void)in_sizes; (void)n_in; (void)out_size; (void)ws_size;
  const float* x    = (const float*)d_in[0];
  const float* w1   = (const float*)d_in[1];
  const float* b1   = (const float*)d_in[2];
  const float* w2   = (const float*)d_in[3];
  const float* b2   = (const float*)d_in[4];
  const float* w3   = (const float*)d_in[5];
  const float* b3   = (const float*)d_in[6];
  const float* wp   = (const float*)d_in[7];
  // d_in[8] = bp : cancels analytically (pe - unfolded pe), unused
  const float* fcw  = (const float*)d_in[9];
  const float* depw = (const float*)d_in[10];
  const float* depb = (const float*)d_in[11];
  const float* r1p  = (const float*)d_in[12];
  const float* r2p  = (const float*)d_in[13];
  float* out = (float*)d_out;

  char* ws = (char*)d_ws;
  u16*   Wall = (u16*)(ws);                 // 896*256*2 = 458,752 B
  float* ball = (float*)(ws + 458752);      // 896*4     =   3,584 B

  k_build<<<dim3(896, 1, 1), 256, 0, stream>>>(w1, b1, w2, b2, w3, b3, fcw, Wall, ball);
  fused_acmix<<<dim3(512, 1, 1), 256, 0, stream>>>(Wall, ball, x, wp, depw, depb, r1p, r2p, out);
}